// Round 8
// baseline (171.481 us; speedup 1.0000x reference)
//
#include <hip/hip_runtime.h>

#define N_CELL 8192
#define N_DRUG 4096

typedef float f32x4 __attribute__((ext_vector_type(4)));

// Output layout (floats):
//   0                       : agg_cell_lp [N_CELL][N_DRUG]
//   OFF1 = N_CELL*N_DRUG    : agg_drug_lp [N_DRUG][N_CELL]
//   OFF2 = 2*N_CELL*N_DRUG  : self_cell_lp [N_CELL][N_CELL]
//   OFF3 = OFF2 + N_CELL^2  : self_drug_lp [N_DRUG][N_DRUG]
static constexpr size_t OFF1 = (size_t)N_CELL * N_DRUG;
static constexpr size_t OFF2 = 2ull * N_CELL * N_DRUG;
static constexpr size_t OFF3 = OFF2 + (size_t)N_CELL * N_CELL;
static constexpr size_t FILL_F4 = ((size_t)N_CELL * N_CELL + (size_t)N_DRUG * N_DRUG) / 4; // 20,971,520

// ---- D1 (unchanged from R7, 153us proven): 512 sums + 1280 fill blocks, 262KB each ----
#define SUM_BLOCKS 512
#define FILL_BLOCKS 1280
#define MEGA_BLOCKS (SUM_BLOCKS + FILL_BLOCKS)
static constexpr size_t FILL_PER_BLOCK = FILL_F4 / FILL_BLOCKS;  // 16384 f4 = 256KB, exact

__global__ __launch_bounds__(256, 8) void mega_kernel(const float* __restrict__ adj,
                                                      float* __restrict__ rowsum,
                                                      float* __restrict__ colsum,
                                                      float* __restrict__ fill_base) {
    int b = blockIdx.x;
    int tid = threadIdx.x;
    if (b >= SUM_BLOCKS) {
        f32x4 z = {0.f, 0.f, 0.f, 0.f};
        f32x4* p = reinterpret_cast<f32x4*>(fill_base) + (size_t)(b - SUM_BLOCKS) * FILL_PER_BLOCK;
#pragma unroll 4
        for (size_t i = tid; i < FILL_PER_BLOCK; i += 256) {
            __builtin_nontemporal_store(z, p + i);
        }
        return;
    }
    __shared__ float part[64][65];
    int cb = b & 3, rb = b >> 2;
    int c0 = cb * 1024, r0 = rb * 64;
    const f32x4* ap = reinterpret_cast<const f32x4*>(adj + (size_t)r0 * N_DRUG + c0) + tid;
    f32x4 cacc = {0.f, 0.f, 0.f, 0.f};
#pragma unroll 4
    for (int r = 0; r < 64; ++r) {
        f32x4 v = ap[(size_t)r * (N_DRUG / 4)];
        cacc += v;
        float h = (v.x + v.y) + (v.z + v.w);
        h += __shfl_down(h, 1, 64);
        h += __shfl_down(h, 2, 64);     // lanes ≡0 mod 4 hold 16-col partials
        if ((tid & 3) == 0) part[r][tid >> 2] = h;
    }
    __syncthreads();
    if (tid < 64) {
        float s = 0.f;
#pragma unroll 8
        for (int j = 0; j < 64; ++j) s += part[tid][j];
        atomicAdd(&rowsum[r0 + tid], s);  // 4 partials per row
    }
    int c = c0 + tid * 4;
    atomicAdd(&colsum[c + 0], cacc.x);    // 128 partials per col
    atomicAdd(&colsum[c + 1], cacc.y);
    atomicAdd(&colsum[c + 2], cacc.z);
    atomicAdd(&colsum[c + 3], cacc.w);
}

// ---- D2: 128x128 tiles, full-tile 64KB LDS stage (XOR-swizzled, conflict-free
// both sides, no pad). Wave-instructions move 2x512B contiguous chunks for the
// adj read, agg_cell write, and transposed agg_drug write. ----
#define SCALE_TILES 2048   // 32 col-tiles x 64 row-tiles
#define DIAG_BLOCKS 48     // 48*256 = 12288 = N_CELL + N_DRUG

// swizzled column: bijective per row; write banks (4(tx&7)+j)^(tx>>3) and read
// banks tx2^const are both 32-distinct -> conflict-free.
__device__ __forceinline__ int swz(int r, int c) {
    return c ^ ((r >> 2) & 31) ^ (c >> 5);
}

__global__ __launch_bounds__(256) void scale_kernel(const float* __restrict__ adj,
                                                    const float* __restrict__ rowsum,
                                                    const float* __restrict__ colsum,
                                                    float* __restrict__ out) {
    int tid = threadIdx.x;
    int b = blockIdx.x;
    if (b >= SCALE_TILES) {  // diag role (fill completed in D1)
        int idx = (b - SCALE_TILES) * 256 + tid;
        if (idx < N_CELL) {
            out[OFF2 + (size_t)idx * (N_CELL + 1)] = 1.0f / (rowsum[idx] + 1.0f) + 1.0f;
        } else {
            int k = idx - N_CELL;   // < N_DRUG by construction
            out[OFF3 + (size_t)k * (N_DRUG + 1)] = 1.0f / (colsum[k] + 1.0f) + 1.0f;
        }
        return;
    }
    __shared__ float lds[128][128];   // exactly 64KB
    int c0 = (b & 31) * 128;   // 32 col-tiles
    int r0 = (b >> 5) * 128;   // 64 row-tiles

    // Phase 1: read adj (nt), scale, write agg_cell (nt), stage swizzled in LDS.
    int tx = tid & 31;         // f4 column within tile (32 x 16B = 512B/row)
    int ty = tid >> 5;         // 0..7
    f32x4 cs = *reinterpret_cast<const f32x4*>(colsum + c0 + tx * 4);
    f32x4 dy;
    dy.x = rsqrtf(cs.x + 1.0f);
    dy.y = rsqrtf(cs.y + 1.0f);
    dy.z = rsqrtf(cs.z + 1.0f);
    dy.w = rsqrtf(cs.w + 1.0f);
    int cbase = tx * 4;
#pragma unroll 4
    for (int i = 0; i < 16; ++i) {
        int rr = i * 8 + ty;
        int r = r0 + rr;
        float dx = rsqrtf(rowsum[r] + 1.0f);
        const f32x4* src = reinterpret_cast<const f32x4*>(adj + (size_t)r * N_DRUG + c0 + cbase);
        f32x4 v = __builtin_nontemporal_load(src);
        f32x4 o = v * dx;
        o *= dy;
        __builtin_nontemporal_store(
            o, reinterpret_cast<f32x4*>(out + (size_t)r * N_DRUG + c0 + cbase));
        lds[rr][swz(rr, cbase + 0)] = o.x;
        lds[rr][swz(rr, cbase + 1)] = o.y;
        lds[rr][swz(rr, cbase + 2)] = o.z;
        lds[rr][swz(rr, cbase + 3)] = o.w;
    }
    __syncthreads();

    // Phase 2: transposed agg_drug writes, 2x512B per wave-instruction.
    float* aggd = out + OFF1;
    int tx2 = tid & 31;        // f4 cell group (32 x 16B = 512B/drug-row)
    int dj = tid >> 5;         // 0..7
#pragma unroll 4
    for (int i = 0; i < 16; ++i) {
        int dd = i * 8 + dj;
        f32x4 o;
        o.x = lds[tx2 * 4 + 0][swz(tx2 * 4 + 0, dd)];
        o.y = lds[tx2 * 4 + 1][swz(tx2 * 4 + 1, dd)];
        o.z = lds[tx2 * 4 + 2][swz(tx2 * 4 + 2, dd)];
        o.w = lds[tx2 * 4 + 3][swz(tx2 * 4 + 3, dd)];
        __builtin_nontemporal_store(
            o, reinterpret_cast<f32x4*>(aggd + (size_t)(c0 + dd) * N_CELL + r0 + tx2 * 4));
    }
}

extern "C" void kernel_launch(void* const* d_in, const int* in_sizes, int n_in,
                              void* d_out, int out_size, void* d_ws, size_t ws_size,
                              hipStream_t stream) {
    const float* adj = (const float*)d_in[0];
    float* out = (float*)d_out;
    float* rowsum = (float*)d_ws;        // N_CELL floats
    float* colsum = rowsum + N_CELL;     // N_DRUG floats

    // zero the atomic accumulators (contiguous 48 KB)
    (void)hipMemsetAsync(d_ws, 0, (N_CELL + N_DRUG) * sizeof(float), stream);

    mega_kernel<<<MEGA_BLOCKS, 256, 0, stream>>>(adj, rowsum, colsum, out + OFF2);
    scale_kernel<<<SCALE_TILES + DIAG_BLOCKS, 256, 0, stream>>>(adj, rowsum, colsum, out);
}